// Round 12
// baseline (880.866 us; speedup 1.0000x reference)
//
#include <hip/hip_runtime.h>
#include <hip/hip_fp16.h>
#include <math.h>

#define WW 128
#define HH 128
#define DD 128
#define HW (WW * HH)
#define VOL (WW * HH * DD)
// padded (halo) geometry: 130^3, interior voxel (d,h,w) -> padded (d+1,h+1,w+1)
#define PW 130
#define PHW (130 * 130)
#define PVOL (130 * 130 * 130)
#define NSHELL 99848   // 130^3 - 128^3

typedef _Float16 f16x8 __attribute__((ext_vector_type(8)));
typedef _Float16 f16x4 __attribute__((ext_vector_type(4)));
typedef _Float16 f16x2 __attribute__((ext_vector_type(2)));
typedef float f32x4 __attribute__((ext_vector_type(4)));
typedef float f32x16 __attribute__((ext_vector_type(16)));
typedef int int4v __attribute__((ext_vector_type(4)));

__device__ __forceinline__ void stv(float* p, float v) { *p = v; }
__device__ __forceinline__ void stv(_Float16* p, float v) { *p = (_Float16)v; }

// weight-field slot for tap m (conv27 stores in MFMA 32x32 C-layout order):
// row m held by lane-half (m>>2)&1, reg r with r&3=m&3, r>>2=m>>3.
#define WPOS(m) ((((m) >> 2) & 1) * 16 + ((m) >> 3) * 4 + ((m) & 3))

// ==========================================================================
// zero_shell: zero only the 1-voxel pad shell of a padded volume.
// ==========================================================================
template <int NCH>
__global__ __launch_bounds__(256) void zero_shell(_Float16* __restrict__ p)
{
    const int t = blockIdx.x * 256 + threadIdx.x;
    if (t >= NSHELL) return;
    int d, h, w;
    if (t < 33800)      { d = (t < 16900) ? 0 : 129; int r = t % 16900; h = r / 130; w = r % 130; }
    else if (t < 67080) { int r = t - 33800; h = (r < 16640) ? 0 : 129; int q = r % 16640; d = 1 + q / 130; w = q % 130; }
    else                { int r = t - 67080; w = (r < 16384) ? 0 : 129; int q = r % 16384; d = 1 + q / 128; h = 1 + q % 128; }
    const size_t site = (size_t)d * PHW + (size_t)h * PW + w;
    if (NCH == 8) *(f16x8*)(p + site * 8) = (f16x8){};
    else          p[site] = (_Float16)0.f;
}

// ==========================================================================
// cvt_x: planar fp32 (8ch) -> channel-interleaved f16x8, PADDED layout
// ==========================================================================
__global__ __launch_bounds__(256) void cvt_x(const float* __restrict__ x,
                                             _Float16* __restrict__ xi)
{
    const size_t v = (size_t)blockIdx.x * 256 + threadIdx.x;
    const int d = (int)(v >> 14), h = (int)((v >> 7) & 127), w = (int)(v & 127);
    f16x8 o;
#pragma unroll
    for (int c = 0; c < 8; ++c) o[c] = (_Float16)x[(size_t)c * VOL + v];
    *(f16x8*)(xi + ((size_t)(d + 1) * PHW + (size_t)(h + 1) * PW + (w + 1)) * 8) = o;
}

// ==========================================================================
// prepack_all: pack conv weights into exact MFMA A-fragment lane order.
// blocks 0-4 (16x16, OC<=16): e=s*64+lane, s=0..6:
//   a[j] = wt[m*216 + j*27 + tap], m=lane&15, tap=s*4+(lane>>4)
// blocks 5-7 (32x32, OC=27): e=s*64+lane, s=0..13:
//   a[j] = wt[m*216 + j*27 + tap], m=lane&31, tap=2*s+(lane>>5)
// ==========================================================================
__global__ __launch_bounds__(256) void prepack_all(
    const float* __restrict__ w0, const float* __restrict__ w1,
    const float* __restrict__ w2, const float* __restrict__ w3,
    const float* __restrict__ w4, const float* __restrict__ w5,
    const float* __restrict__ w6, const float* __restrict__ w7,
    _Float16* __restrict__ pb)
{
    const int b = blockIdx.x;
    const float* src; int OC; size_t off;
    switch (b) {
        case 0: src = w0; OC = 8;  off = 0;     break;
        case 1: src = w1; OC = 8;  off = 3584;  break;
        case 2: src = w2; OC = 8;  off = 7168;  break;
        case 3: src = w3; OC = 8;  off = 10752; break;
        case 4: src = w4; OC = 1;  off = 14336; break;
        case 5: src = w5; OC = 27; off = 17920; break;
        case 6: src = w6; OC = 27; off = 25088; break;
        default: src = w7; OC = 27; off = 32256; break;
    }
    const bool big = (b >= 5);
    const int total = big ? 896 : 448;
    for (int e = threadIdx.x; e < total; e += 256) {
        const int s = e >> 6, lane = e & 63;
        const int m   = big ? (lane & 31) : (lane & 15);
        const int tap = big ? (2 * s + (lane >> 5)) : (s * 4 + (lane >> 4));
        f16x8 a = {};
        if (tap < 27 && m < OC) {
#pragma unroll
            for (int j = 0; j < 8; ++j)
                a[j] = (_Float16)src[m * 216 + j * 27 + tap];
        }
        *(f16x8*)(pb + off + (size_t)e * 8) = a;
    }
}

// ==========================================================================
// conv_g: implicit-GEMM 3x3x3 conv via MFMA 16x16x32 f16, OC<=16.
// No LDS / no barriers / no bounds checks (padded input).
// OM: 0 = padded interleaved 8-ch out, 2 = padded planar 1-ch out.
// ==========================================================================
template <int OC, bool RELU, int OM, typename TO>
__global__ __launch_bounds__(256) void conv_g(const _Float16* __restrict__ in,
                                              const _Float16* __restrict__ apack,
                                              const float* __restrict__ bias,
                                              TO* __restrict__ out)
{
    const int tid  = threadIdx.x;
    const int wid  = tid >> 6;
    const int lane = tid & 63;
    const int n    = lane & 15;
    const int quad = lane >> 4;

    const int bid = blockIdx.x;            // 4096 blocks x 4 waves = 16384 (d,h) rows
    const int idx = bid >> 3;
    const int d   = ((bid & 7) << 4) + (idx & 15);
    const int h   = ((idx >> 4) << 2) + wid;

    f16x8 afr[7];
#pragma unroll
    for (int s = 0; s < 7; ++s)
        afr[s] = *(const f16x8*)(apack + (size_t)(s * 64 + lane) * 8);

    int voff[7];
#pragma unroll
    for (int s = 0; s < 7; ++s) {
        int tap = s * 4 + quad;
        if (tap > 26) tap = 26;            // A is zero there
        const int kd = tap / 9, kh = (tap % 9) / 3, kw = tap % 3;
        voff[s] = (d + kd) * PHW + (h + kh) * PW + kw;
    }

    float bv[4];
#pragma unroll
    for (int r = 0; r < 4; ++r) {
        const int o = quad * 4 + r;
        bv[r] = (bias != nullptr && o < OC) ? bias[o] : 0.f;
    }

#pragma unroll 2
    for (int wseg = 0; wseg < 8; ++wseg) {
        const int wv = wseg * 16 + n;
        f16x8 bfr[7];
#pragma unroll
        for (int s = 0; s < 7; ++s)
            bfr[s] = *(const f16x8*)(in + (size_t)(voff[s] + wv) * 8);
        f32x4 acc;
        acc[0] = bv[0]; acc[1] = bv[1]; acc[2] = bv[2]; acc[3] = bv[3];
#pragma unroll
        for (int s = 0; s < 7; ++s)
            acc = __builtin_amdgcn_mfma_f32_16x16x32_f16(afr[s], bfr[s], acc, 0, 0, 0);

        if (OM == 0) {
            if (quad < 2) {
                const size_t pvox = (size_t)(d + 1) * PHW + (size_t)(h + 1) * PW + 1 + wv;
                f16x4 o4;
#pragma unroll
                for (int r = 0; r < 4; ++r) {
                    float v = acc[r];
                    if (RELU) v = fmaxf(v, 0.f);
                    o4[r] = (_Float16)v;
                }
                *(f16x4*)((_Float16*)out + pvox * 8 + quad * 4) = o4;
            }
        } else { // OM == 2, OC = 1, padded planar out
            if (quad == 0) {
                const size_t pvox = (size_t)(d + 1) * PHW + (size_t)(h + 1) * PW + 1 + wv;
                float v = acc[0];
                if (RELU) v = fmaxf(v, 0.f);
                stv((TO*)out + pvox, v);
            }
        }
    }
}

// ==========================================================================
// conv27_g: 8->27 weight conv via MFMA 32x32x16 f16 + L1-normalize.
// 14 MFMAs per 32 voxels; C-regs stored directly in C-layout order (WPOS).
// R12: wseg loop unroll 2 -> compiler software-pipelines the 14 B-loads
// across iterations (R11's unroll 1 blocked it; kernel was latency-bound).
// ==========================================================================
__global__ __launch_bounds__(256) void conv27_g(const _Float16* __restrict__ in,
                                                const _Float16* __restrict__ apack,
                                                _Float16* __restrict__ wn)
{
    const int tid  = threadIdx.x;
    const int wid  = tid >> 6;
    const int lane = tid & 63;
    const int col  = lane & 31;
    const int half = lane >> 5;

    const int bid = blockIdx.x;            // 4096 blocks x 4 waves = 16384 (d,h) rows
    const int idx = bid >> 3;
    const int d   = ((bid & 7) << 4) + (idx & 15);
    const int h   = ((idx >> 4) << 2) + wid;

    f16x8 afr[14];
#pragma unroll
    for (int s = 0; s < 14; ++s)
        afr[s] = *(const f16x8*)(apack + (size_t)(s * 64 + lane) * 8);

    int voff[14];
#pragma unroll
    for (int s = 0; s < 14; ++s) {
        int tap = 2 * s + half;
        if (tap > 26) tap = 26;            // A row zero there
        const int kd = tap / 9, kh = (tap % 9) / 3, kw = tap % 3;
        voff[s] = (d + kd) * PHW + (h + kh) * PW + kw;
    }

#pragma unroll 2
    for (int wseg = 0; wseg < 4; ++wseg) {
        const int wv = wseg * 32 + col;
        f16x8 bfr[14];
#pragma unroll
        for (int s = 0; s < 14; ++s)
            bfr[s] = *(const f16x8*)(in + (size_t)(voff[s] + wv) * 8);
        f32x16 acc = {};
#pragma unroll
        for (int s = 0; s < 14; ++s)
            acc = __builtin_amdgcn_mfma_f32_32x32x16_f16(afr[s], bfr[s], acc, 0, 0, 0);

        float p0 = (fabsf(acc[0]) + fabsf(acc[1])) + (fabsf(acc[2]) + fabsf(acc[3]));
        float p1 = (fabsf(acc[4]) + fabsf(acc[5])) + (fabsf(acc[6]) + fabsf(acc[7]));
        float p2 = (fabsf(acc[8]) + fabsf(acc[9])) + (fabsf(acc[10]) + fabsf(acc[11]));
        float p3 = (fabsf(acc[12]) + fabsf(acc[13])) + (fabsf(acc[14]) + fabsf(acc[15]));
        float ssum = (p0 + p1) + (p2 + p3);
        ssum += __shfl_xor(ssum, 32);
        const float inv = __builtin_amdgcn_rcpf(fmaxf(ssum, 1e-12f));

        int pk[8];
#pragma unroll
        for (int i = 0; i < 8; ++i) {
            f16x2 t;
            t[0] = (_Float16)(acc[2 * i] * inv);
            t[1] = (_Float16)(acc[2 * i + 1] * inv);
            pk[i] = __builtin_bit_cast(int, t);
        }
        const size_t vox = (size_t)d * HW + (size_t)h * WW + wv;   // unpadded
        _Float16* dst = wn + (vox << 5) + (half << 4);
        int4v v0; v0[0] = pk[0]; v0[1] = pk[1]; v0[2] = pk[2]; v0[3] = pk[3];
        int4v v1; v1[0] = pk[4]; v1[1] = pk[5]; v1[2] = pk[6]; v1[3] = pk[7];
        *(int4v*)dst = v0;
        *(int4v*)(dst + 8) = v1;
    }
}

// ==========================================================================
// adapt8: per-voxel 27-tap weights (unpadded [vox][32] fp16, C-layout order
// via WPOS), 8 interleaved channels, PADDED in/out.
// R12: 2 voxels per thread along h (w-coalescing preserved) — the 3x4x3
// shared row loads serve both voxels: 18 loads/voxel instead of 27,
// 16 independent acc chains. Per-voxel tap accumulation order unchanged.
// ==========================================================================
__global__ __launch_bounds__(256) void adapt8(const _Float16* __restrict__ in,
                                              const _Float16* __restrict__ wn,
                                              _Float16* __restrict__ out)
{
    const int tid = threadIdx.x;
    const int bid = blockIdx.x;            // 4096 = 128 d x 32 h-quads
    const int d  = bid >> 5;
    const int h0 = ((bid & 31) << 2) + ((tid >> 7) << 1);   // voxels (h0, h0+1)
    const int w  = tid & 127;
    const size_t vox0 = (size_t)d * HW + (size_t)h0 * WW + w;   // unpadded (weights)

    f16x8 wk0[4], wk1[4];
    {
        const f16x8* wr0 = (const f16x8*)(wn + (vox0 << 5));
        const f16x8* wr1 = (const f16x8*)(wn + ((vox0 + WW) << 5));
#pragma unroll
        for (int j = 0; j < 4; ++j) { wk0[j] = wr0[j]; wk1[j] = wr1[j]; }
    }

    float acc0[8] = {0.f, 0.f, 0.f, 0.f, 0.f, 0.f, 0.f, 0.f};
    float acc1[8] = {0.f, 0.f, 0.f, 0.f, 0.f, 0.f, 0.f, 0.f};
#pragma unroll
    for (int kd = 0; kd < 3; ++kd) {
#pragma unroll
        for (int r = 0; r < 4; ++r) {      // padded h row h0+r covers kh=r for v0, r-1 for v1
            const _Float16* rp = in + ((size_t)(d + kd) * PHW + (size_t)(h0 + r) * PW + w) * 8;
            f16x8 xs[3];
#pragma unroll
            for (int kw = 0; kw < 3; ++kw)
                xs[kw] = *(const f16x8*)(rp + (size_t)kw * 8);
            if (r < 3) {                   // voxel0, kh = r
#pragma unroll
                for (int kw = 0; kw < 3; ++kw) {
                    const int t = WPOS(kd * 9 + r * 3 + kw);
                    const float wvv = (float)wk0[t >> 3][t & 7];
#pragma unroll
                    for (int c = 0; c < 8; ++c) acc0[c] += wvv * (float)xs[kw][c];
                }
            }
            if (r >= 1) {                  // voxel1, kh = r-1
#pragma unroll
                for (int kw = 0; kw < 3; ++kw) {
                    const int t = WPOS(kd * 9 + (r - 1) * 3 + kw);
                    const float wvv = (float)wk1[t >> 3][t & 7];
#pragma unroll
                    for (int c = 0; c < 8; ++c) acc1[c] += wvv * (float)xs[kw][c];
                }
            }
        }
    }
    f16x8 o0, o1;
#pragma unroll
    for (int c = 0; c < 8; ++c) { o0[c] = (_Float16)acc0[c]; o1[c] = (_Float16)acc1[c]; }
    _Float16* ob = out + ((size_t)(d + 1) * PHW + (size_t)(h0 + 1) * PW + (w + 1)) * 8;
    *(f16x8*)ob = o0;
    *(f16x8*)(ob + (size_t)PW * 8) = o1;
}

// ==========================================================================
// adapt1: 1 channel, PADDED planar f16 in; weights unpadded [vox][32]
// (C-layout order via WPOS). PADOUT: padded f16 out, else unpadded out.
// ==========================================================================
template <bool PADOUT, typename TOUT>
__global__ __launch_bounds__(256) void adapt1(const _Float16* __restrict__ in,
                                              const _Float16* __restrict__ wn,
                                              TOUT* __restrict__ out)
{
    const size_t vox = (size_t)blockIdx.x * 256 + threadIdx.x;
    const int w = (int)(vox & 127);
    const int h = (int)((vox >> 7) & 127);
    const int d = (int)(vox >> 14);

    const f16x8* wrow = (const f16x8*)(wn + (vox << 5));
    f16x8 wkv[4];
#pragma unroll
    for (int j = 0; j < 4; ++j) wkv[j] = wrow[j];

    float acc = 0.f;
#pragma unroll
    for (int kd = 0; kd < 3; ++kd) {
#pragma unroll
        for (int kh = 0; kh < 3; ++kh) {
            const _Float16* rp = in + (size_t)(d + kd) * PHW + (size_t)(h + kh) * PW + w;
#pragma unroll
            for (int kw = 0; kw < 3; ++kw) {
                const int t = WPOS(kd * 9 + kh * 3 + kw);
                acc += (float)wkv[t >> 3][t & 7] * (float)rp[kw];
            }
        }
    }
    if (PADOUT)
        stv(out + (size_t)(d + 1) * PHW + (size_t)(h + 1) * PW + (w + 1), acc);
    else
        stv(out + vox, acc);
}

extern "C" void kernel_launch(void* const* d_in, const int* in_sizes, int n_in,
                              void* d_out, int out_size, void* d_ws, size_t ws_size,
                              hipStream_t stream)
{
    (void)in_sizes; (void)n_in; (void)out_size; (void)ws_size;

    const float* x      = (const float*)d_in[0];
    const float* ac1_w1 = (const float*)d_in[1];
    const float* ac1_b1 = (const float*)d_in[2];
    const float* ac1_w2 = (const float*)d_in[3];
    const float* ac2_w1 = (const float*)d_in[4];
    const float* ac2_b1 = (const float*)d_in[5];
    const float* ac2_w2 = (const float*)d_in[6];
    const float* ac3_w1 = (const float*)d_in[7];
    const float* ac3_b1 = (const float*)d_in[8];
    const float* ac3_w2 = (const float*)d_in[9];
    const float* mid_w  = (const float*)d_in[10];
    const float* mid_b  = (const float*)d_in[11];
    const float* out_w  = (const float*)d_in[12];
    const float* out_b  = (const float*)d_in[13];
    float* outp = (float*)d_out;

    // fp16 scratch (213 MB, ws >= 236 MB per R2 forensics):
    // Wb [vox][32] (32V) | B1i 8*PVOL | B2i 8*PVOL | F0 PVOL | F1 PVOL | packs
    const size_t V = (size_t)VOL;
    _Float16* Wb  = (_Float16*)d_ws;
    _Float16* B1i = Wb + 32 * V;
    _Float16* B2i = B1i + (size_t)8 * PVOL;
    _Float16* F0  = B2i + (size_t)8 * PVOL;
    _Float16* F1  = F0 + (size_t)PVOL;
    _Float16* PB  = F1 + (size_t)PVOL;

    _Float16* pk_ac1w1 = PB + 0;
    _Float16* pk_ac2w1 = PB + 3584;
    _Float16* pk_ac3w1 = PB + 7168;
    _Float16* pk_midw  = PB + 10752;
    _Float16* pk_outw  = PB + 14336;
    _Float16* pk_ac1w2 = PB + 17920;
    _Float16* pk_ac2w2 = PB + 25088;
    _Float16* pk_ac3w2 = PB + 32256;

    const dim3 cgrid(4096), cblk(256);
    const dim3 a8grid(4096), a8blk(256);
    const dim3 a1grid(8192), a1blk(256);
    const dim3 zgrid((NSHELL + 255) / 256), zblk(256);

    zero_shell<8><<<zgrid, zblk, 0, stream>>>(B1i);
    zero_shell<8><<<zgrid, zblk, 0, stream>>>(B2i);
    zero_shell<1><<<zgrid, zblk, 0, stream>>>(F0);
    zero_shell<1><<<zgrid, zblk, 0, stream>>>(F1);
    prepack_all<<<8, 256, 0, stream>>>(ac1_w1, ac2_w1, ac3_w1, mid_w, out_w,
                                       ac1_w2, ac2_w2, ac3_w2, PB);
    cvt_x<<<8192, 256, 0, stream>>>(x, B2i);                                   // B2i = x

    // ---- adaptive block 1 (input x = B2i) ----
    conv_g<8, true, 0, _Float16><<<cgrid, cblk, 0, stream>>>(B2i, pk_ac1w1, ac1_b1, B1i);
    conv27_g<<<cgrid, cblk, 0, stream>>>(B1i, pk_ac1w2, Wb);
    adapt8<<<a8grid, a8blk, 0, stream>>>(B2i, Wb, B1i);
    adapt8<<<a8grid, a8blk, 0, stream>>>(B1i, Wb, B2i);
    adapt8<<<a8grid, a8blk, 0, stream>>>(B2i, Wb, B1i);                        // B1i = block1 out
    conv_g<8, false, 0, _Float16><<<cgrid, cblk, 0, stream>>>(B1i, pk_midw, mid_b, B2i); // B2i = mid

    // ---- adaptive block 2 (input mid = B2i) ----
    conv_g<8, true, 0, _Float16><<<cgrid, cblk, 0, stream>>>(B2i, pk_ac2w1, ac2_b1, B1i);
    conv27_g<<<cgrid, cblk, 0, stream>>>(B1i, pk_ac2w2, Wb);
    adapt8<<<a8grid, a8blk, 0, stream>>>(B2i, Wb, B1i);
    adapt8<<<a8grid, a8blk, 0, stream>>>(B1i, Wb, B2i);
    adapt8<<<a8grid, a8blk, 0, stream>>>(B2i, Wb, B1i);                        // B1i = mid2

    // ---- block 3: weights from mid2 = B1i ----
    conv_g<8, true, 0, _Float16><<<cgrid, cblk, 0, stream>>>(B1i, pk_ac3w1, ac3_b1, B2i);
    conv27_g<<<cgrid, cblk, 0, stream>>>(B2i, pk_ac3w2, Wb);
    conv_g<1, false, 2, _Float16><<<cgrid, cblk, 0, stream>>>(B1i, pk_outw, out_b, F0);
    adapt1<true, _Float16><<<a1grid, a1blk, 0, stream>>>(F0, Wb, F1);
    adapt1<true, _Float16><<<a1grid, a1blk, 0, stream>>>(F1, Wb, F0);
    adapt1<false, float><<<a1grid, a1blk, 0, stream>>>(F0, Wb, outp);
}